// Round 5
// baseline (450.565 us; speedup 1.0000x reference)
//
#include <hip/hip_runtime.h>
#include <hip/hip_fp16.h>

// MaxUnpooling2D scatter-add, LDS-bucketed binning with full-line flushes.
//
// updates: [16,128,128,64] fp32 = 2^24 elements (64 MiB)
// mask:    int32-staged, values in [0, 2^22) per batch
// out:     [16,256,256,64] fp32 = 2^26 elements (256 MiB)
//
// Round-10. Round-9 (443 us total, ~200 us controllable after ~240 us fixed
// poison/restore) proved the LDS-bucket full-line-flush design: write amp
// gone, both kernels < 165 us. Remaining theory:
//  (a) DRAIN's rebase loop was a runtime-count serial LDS chain (~14 x
//      ~120cy dependent read->write) sitting on every phase's critical
//      path. Now: 14 unconditional reads into registers (slots 16..29
//      always in-bounds), one wait, 14 predicated writes.
//  (b) accum streamed full 128-slot capacity (2x the live records, dead
//      half on separate 64-B lines). Now: exec-masked loads skip groups
//      past ceil(n/4) -> ~60 MB less fetch.
// Structure otherwise unchanged:
//  - bkt [30 slots][512 bins] = 60 KiB (+2 KiB lcnt); drain reads
//    bkt[s*512+t] lane-consecutive = conflict-free.
//  - barriers on BOTH sides of drain; 64 phases of 512 inserts
//    (lambda=1/bin), threshold 16, depth 30 -> overflow p ~ 2e-8/run.
//  - records [batch][lb][chunk][slot]: accum reads one contiguous 16-KiB
//    region per bin, coalesced. cnt [batch][cc][lb]: coalesced writes.
//  - 4-byte records: (13-bit bin-local offset << 16) | fp16 value.

#define N_ELEMS   (1u << 24)

// binplace geometry
#define NB        512                    // chunks (32 per batch)
#define BPT       512                    // binplace block size
#define G4_PER_B  ((N_ELEMS / NB) / 4)   // 8192 int4 groups per chunk
#define BP_ITERS  (G4_PER_B / BPT)       // 16

// binning geometry
#define BIN_SHIFT 13                     // 8192 floats (32 KiB) out-region per bin
#define LBINS     512                    // bins per batch
#define LBIN_SH   9
#define NBINS     8192                   // 16 batches * 512
#define CAP_SHIFT 7                      // 128 record slots per (bin,chunk) segment
#define CAP       (1u << CAP_SHIFT)
#define SEGS      32                     // chunks per batch
#define SEG_SH    5

#define BKT_DEPTH 30u                    // LDS bucket slots per bin

#define ACC_T     512                    // accum block size

typedef float    floatx4 __attribute__((ext_vector_type(4)));
typedef unsigned uintx4  __attribute__((ext_vector_type(4)));

// ---------------- fallback (round-2 design) ----------------

__global__ __launch_bounds__(256) void zero_out_kernel(float4* __restrict__ out, int n4)
{
    int i = blockIdx.x * blockDim.x + threadIdx.x;
    if (i < n4) out[i] = make_float4(0.f, 0.f, 0.f, 0.f);
}

__global__ __launch_bounds__(256) void maxunpool_scatter_kernel(
    const float4* __restrict__ upd, const int4* __restrict__ mask,
    float* __restrict__ out, int n4)
{
    int i = blockIdx.x * blockDim.x + threadIdx.x;
    if (i >= n4) return;
    float4 u = upd[i];
    int4   m = mask[i];
    long long base = (long long)(i >> 18) << 22;
    atomicAdd(out + base + m.x, u.x);
    atomicAdd(out + base + m.y, u.y);
    atomicAdd(out + base + m.z, u.z);
    atomicAdd(out + base + m.w, u.w);
}

// ---------------- binned pipeline ----------------

// records word offset: batch<<21 | lb<<12 | cc<<7 | slot  (2^25 words = 128 MiB)
// cnt     word offset: batch<<14 | cc<<9  | lb            (2^18 words = 1 MiB)

__global__ __launch_bounds__(BPT) void binplace_kernel(
    const float4* __restrict__ upd4, const int4* __restrict__ mask4,
    unsigned* __restrict__ cnt, unsigned* __restrict__ records)
{
    __shared__ unsigned bkt[BKT_DEPTH * LBINS];   // 60 KiB, [slot][bin]
    __shared__ unsigned lcnt[LBINS];              // 2 KiB, records in bucket
    const int t = threadIdx.x;
    lcnt[t] = 0u;
    __syncthreads();

    const unsigned chunk = blockIdx.x;
    const unsigned batch = chunk >> SEG_SH;
    const unsigned cc    = chunk & (SEGS - 1u);
    const int4*   m4 = mask4 + (size_t)chunk * G4_PER_B;
    const float4* u4 = upd4  + (size_t)chunk * G4_PER_B;

    // this thread's drain target: segment (batch, lb=t, cc)
    unsigned* __restrict__ segp =
        records + (batch << 21) + ((unsigned)t << 12) + (cc << CAP_SHIFT);
    unsigned gout = 0u;                           // flushed records (global cursor)

#define INSERT(m_, v_) do {                                                  \
        unsigned g_i  = (unsigned)(m_);                                      \
        unsigned lb_i = g_i >> BIN_SHIFT;                                    \
        unsigned pos_i = atomicAdd(&lcnt[lb_i], 1u);                         \
        if (pos_i < BKT_DEPTH)                                               \
            bkt[pos_i * LBINS + lb_i] =                                      \
                ((g_i & ((1u << BIN_SHIFT) - 1u)) << 16) |                   \
                (unsigned)__half_as_ushort(__float2half_rn(v_));             \
    } while (0)

    // Drain one full 16-record group (64 B) if present; rebase remainder.
    // Rebase is latency-flat: 14 unconditional independent LDS reads
    // (slots 16..29 always in-bounds) -> one wait -> 14 predicated writes.
    // Barriers on BOTH sides: next-phase inserts must not race the drain.
#define DRAIN() do {                                                         \
        __syncthreads();                                                     \
        unsigned c_d = lcnt[t];                                              \
        if (c_d > BKT_DEPTH) c_d = BKT_DEPTH;                                \
        if (c_d >= 16u) {                                                    \
            if (gout + 16u <= CAP) {                                         \
                uintx4 r0, r1, r2, r3;                                       \
                r0.x = bkt[ 0u*LBINS+t]; r0.y = bkt[ 1u*LBINS+t];            \
                r0.z = bkt[ 2u*LBINS+t]; r0.w = bkt[ 3u*LBINS+t];            \
                r1.x = bkt[ 4u*LBINS+t]; r1.y = bkt[ 5u*LBINS+t];            \
                r1.z = bkt[ 6u*LBINS+t]; r1.w = bkt[ 7u*LBINS+t];            \
                r2.x = bkt[ 8u*LBINS+t]; r2.y = bkt[ 9u*LBINS+t];            \
                r2.z = bkt[10u*LBINS+t]; r2.w = bkt[11u*LBINS+t];            \
                r3.x = bkt[12u*LBINS+t]; r3.y = bkt[13u*LBINS+t];            \
                r3.z = bkt[14u*LBINS+t]; r3.w = bkt[15u*LBINS+t];            \
                uintx4* dst_d = (uintx4*)(segp + gout);                      \
                dst_d[0] = r0; dst_d[1] = r1; dst_d[2] = r2; dst_d[3] = r3;  \
            }                                                                \
            gout += 16u;                                                     \
            unsigned rem_d = c_d - 16u;                                      \
            unsigned tmp_d[14];                                              \
            _Pragma("unroll")                                                \
            for (int i_d = 0; i_d < 14; ++i_d)                               \
                tmp_d[i_d] = bkt[(16u + (unsigned)i_d) * LBINS + t];         \
            _Pragma("unroll")                                                \
            for (int i_d = 0; i_d < 14; ++i_d)                               \
                if ((unsigned)i_d < rem_d)                                   \
                    bkt[(unsigned)i_d * LBINS + t] = tmp_d[i_d];             \
            lcnt[t] = rem_d;                                                 \
        }                                                                    \
        __syncthreads();                                                     \
    } while (0)

    // Software-pipelined input; one insert per thread per phase (64 phases).
    int4   m = m4[t];
    float4 u = u4[t];
    for (int k = 0; k < BP_ITERS; ++k) {
        int4 mn = m; float4 un = u;
        if (k + 1 < BP_ITERS) {
            mn = m4[(k + 1) * BPT + t];
            un = u4[(k + 1) * BPT + t];
        }
        INSERT(m.x, u.x); DRAIN();
        INSERT(m.y, u.y); DRAIN();
        INSERT(m.z, u.z); DRAIN();
        INSERT(m.w, u.w); DRAIN();
        m = mn; u = un;
    }

    // Tail: last DRAIN left < 16 pending for bin t.
    {
        unsigned r = lcnt[t];
        if (r > 15u) r = 15u;
        for (unsigned i = 0u; i < r; ++i)
            if (gout + i < CAP) segp[gout + i] = bkt[i * LBINS + t];
        unsigned total = gout + r;
        if (total > CAP) total = CAP;
        cnt[(batch << (SEG_SH + LBIN_SH)) | (cc << LBIN_SH) | (unsigned)t] = total;
    }
#undef INSERT
#undef DRAIN
}

// One bin (32 KiB out-region) per block; its 32 segments are one contiguous
// 16-KiB region. Loads are exec-masked past each segment's live prefix so
// dead 64-B lines are never fetched. 512 threads + 32 KiB LDS -> 4 blocks/CU.
__global__ __launch_bounds__(ACC_T) void accum_kernel(
    const unsigned* __restrict__ records, const unsigned* __restrict__ cnt,
    float* __restrict__ out)
{
    __shared__ float acc[1 << BIN_SHIFT];     // 32 KiB
    __shared__ unsigned ln[SEGS];
    const int t = threadIdx.x;
    const unsigned bin   = blockIdx.x;        // [0, 8192)
    const unsigned batch = bin >> LBIN_SH;
    const unsigned lb    = bin & (LBINS - 1u);

    floatx4* accv = (floatx4*)acc;
    #pragma unroll
    for (int i = 0; i < (1 << BIN_SHIFT) / 4 / ACC_T; ++i)
        accv[i * ACC_T + t] = (floatx4)(0.f);
    if (t < SEGS)
        ln[t] = cnt[(batch << (SEG_SH + LBIN_SH)) | ((unsigned)t << LBIN_SH) | lb];
    __syncthreads();

    const uintx4* rec = (const uintx4*)(records + ((size_t)bin << (SEG_SH + CAP_SHIFT)));
    #pragma unroll
    for (int i = 0; i < (SEGS << CAP_SHIFT) / 4 / ACC_T; ++i) {   // 2
        unsigned q  = (unsigned)(i * ACC_T + t);    // uintx4 index in [0,1024)
        unsigned s  = q >> (CAP_SHIFT - 2);         // segment 0..31
        unsigned j0 = (q & ((1u << (CAP_SHIFT - 2)) - 1u)) << 2;
        unsigned n  = ln[s];
        if (j0 < n) {                               // skip dead lines entirely
            uintx4 v = __builtin_nontemporal_load(&rec[q]);
            atomicAdd(&acc[v.x >> 16],              // j0 < n guaranteed
                __half2float(__ushort_as_half((unsigned short)(v.x & 0xFFFFu))));
            if (j0 + 1u < n) atomicAdd(&acc[v.y >> 16],
                __half2float(__ushort_as_half((unsigned short)(v.y & 0xFFFFu))));
            if (j0 + 2u < n) atomicAdd(&acc[v.z >> 16],
                __half2float(__ushort_as_half((unsigned short)(v.z & 0xFFFFu))));
            if (j0 + 3u < n) atomicAdd(&acc[v.w >> 16],
                __half2float(__ushort_as_half((unsigned short)(v.w & 0xFFFFu))));
        }
    }
    __syncthreads();

    floatx4* dst = (floatx4*)(out + ((size_t)bin << BIN_SHIFT));
    #pragma unroll
    for (int i = 0; i < (1 << BIN_SHIFT) / 4 / ACC_T; ++i)
        __builtin_nontemporal_store(accv[i * ACC_T + t], &dst[i * ACC_T + t]);
}

// ---------------- launcher ----------------

extern "C" void kernel_launch(void* const* d_in, const int* in_sizes, int n_in,
                              void* d_out, int out_size, void* d_ws, size_t ws_size,
                              hipStream_t stream) {
    const float* upd  = (const float*)d_in[0];
    const int*   mask = (const int*)d_in[1];
    float*       out  = (float*)d_out;

    int n = in_sizes[0];

    // ws layout: cnt (2^18 u32 = 1 MiB) | records (2^25 u32 = 128 MiB)
    size_t off_records = (size_t)1 << 20;
    size_t needed      = off_records + ((size_t)1 << 25) * 4;

    if ((unsigned)n == N_ELEMS && ws_size >= needed) {
        unsigned* cnt     = (unsigned*)d_ws;
        unsigned* records = (unsigned*)((char*)d_ws + off_records);

        binplace_kernel<<<NB,    BPT,   0, stream>>>((const float4*)upd, (const int4*)mask,
                                                     cnt, records);
        accum_kernel   <<<NBINS, ACC_T, 0, stream>>>(records, cnt, out);
    } else {
        // Fallback: zero + direct global atomics (round-2 design).
        int n4   = n / 4;
        int out4 = out_size / 4;
        zero_out_kernel<<<(out4 + 255) / 256, 256, 0, stream>>>((float4*)out, out4);
        maxunpool_scatter_kernel<<<(n4 + 255) / 256, 256, 0, stream>>>(
            (const float4*)upd, (const int4*)mask, out, n4);
    }
}

// Round 7
// 444.164 us; speedup vs baseline: 1.0144x; 1.0144x over previous
//
#include <hip/hip_runtime.h>
#include <hip/hip_fp16.h>

// MaxUnpooling2D scatter-add, LDS-bucketed binning with full-line flushes.
//
// updates: [16,128,128,64] fp32 = 2^24 elements (64 MiB)
// mask:    int32-staged, values in [0, 2^22) per batch
// out:     [16,256,256,64] fp32 = 2^26 elements (256 MiB)
//
// Round-12. Rounds 2/6 both died at launch with >64 KiB static LDS (66/70
// KiB) while 62 KiB ran -- sharedMemPerBlock=64 KiB is a hard cap here.
// This round re-fits round-6's issue-count-cutting design under the cap by
// coarsening bins 2x (BIN_SHIFT 14, 256 bins/batch of 64 KiB out-region):
//  - circular 48-slot buckets, [bin][slot] stride 52 (pad keeps b128 16-B
//    aligned, spreads owner-gather over 8 bank groups): 52 KiB + 1 KiB cd
//    = 53 KiB -> 3 blocks/CU.
//  - slot = pos % 48 (magic-mul); drain cursor d%48 in {0,16,32} so a
//    16-record (64-B) flush group never wraps the ring.
//  - packed counter cd[bin] = count | drained<<16: insert's one ds_add_rtn
//    returns position AND overflow bound (2 ds ops per insert, no rebase).
//  - 2 inserts/phase, 32 phases / 64 barriers; drain only by threads<256
//    (waves 4..7 skip via execz). lambda=4/bin/phase, headroom 32 ->
//    overflow needs >=34 same-bin arrivals in one phase: p ~ 1e-19. Safe.
//  - accum: 64 KiB acc + 1024 threads = 2 blocks/CU, 32 waves (full);
//    per-segment counts read straight from L2 (LDS exactly at cap).
// Records [batch][lb][chunk][slot] (= [bin][chunk][slot]): accum reads one
// contiguous 32-KiB region per bin, exec-masked past each live prefix.
//  - 4-byte records: (14-bit bin-local offset << 16) | fp16 value.

#define N_ELEMS   (1u << 24)

// binplace geometry
#define NB        512                    // chunks (32 per batch)
#define BPT       512                    // binplace block size
#define G4_PER_B  ((N_ELEMS / NB) / 4)   // 8192 int4 groups per chunk
#define BP_ITERS  (G4_PER_B / BPT)       // 16

// binning geometry
#define BIN_SHIFT 14                     // 16384 floats (64 KiB) out-region per bin
#define LBINS     256                    // bins per batch
#define LBIN_SH   8
#define NBINS     4096                   // 16 batches * 256
#define CAP_SHIFT 8                      // 256 record slots per (bin,chunk) segment
#define CAP       (1u << CAP_SHIFT)
#define SEGS      32                     // chunks per batch
#define SEG_SH    5

#define DEPTH     48u                    // circular bucket slots per bin
#define BSTRIDE   52u                    // padded stride (words)

#define ACC_T     1024                   // accum block size

typedef float    floatx4 __attribute__((ext_vector_type(4)));
typedef unsigned uintx4  __attribute__((ext_vector_type(4)));

// ---------------- fallback (round-2 design) ----------------

__global__ __launch_bounds__(256) void zero_out_kernel(float4* __restrict__ out, int n4)
{
    int i = blockIdx.x * blockDim.x + threadIdx.x;
    if (i < n4) out[i] = make_float4(0.f, 0.f, 0.f, 0.f);
}

__global__ __launch_bounds__(256) void maxunpool_scatter_kernel(
    const float4* __restrict__ upd, const int4* __restrict__ mask,
    float* __restrict__ out, int n4)
{
    int i = blockIdx.x * blockDim.x + threadIdx.x;
    if (i >= n4) return;
    float4 u = upd[i];
    int4   m = mask[i];
    long long base = (long long)(i >> 18) << 22;
    atomicAdd(out + base + m.x, u.x);
    atomicAdd(out + base + m.y, u.y);
    atomicAdd(out + base + m.z, u.z);
    atomicAdd(out + base + m.w, u.w);
}

// ---------------- binned pipeline ----------------

// records word offset: batch<<21 | lb<<13 | cc<<8 | slot  (2^25 words = 128 MiB)
// cnt     word offset: batch<<13 | cc<<8  | lb            (2^17 words = 512 KiB)

__global__ __launch_bounds__(BPT) void binplace_kernel(
    const float4* __restrict__ upd4, const int4* __restrict__ mask4,
    unsigned* __restrict__ cnt, unsigned* __restrict__ records)
{
    __shared__ __align__(16) unsigned bkt[LBINS * BSTRIDE];  // 52 KiB
    __shared__ unsigned cd[LBINS];    // 1 KiB: count | drained<<16
    const int t = threadIdx.x;
    if (t < LBINS) cd[t] = 0u;
    __syncthreads();

    const unsigned chunk = blockIdx.x;
    const unsigned batch = chunk >> SEG_SH;
    const unsigned cc    = chunk & (SEGS - 1u);
    const int4*   m4 = mask4 + (size_t)chunk * G4_PER_B;
    const float4* u4 = upd4  + (size_t)chunk * G4_PER_B;

    // owner thread t (< LBINS) drains bin t into segment (batch, lb=t, cc)
    unsigned* __restrict__ segp =
        records + (batch << 21) + ((unsigned)t << 13) + (cc << CAP_SHIFT);

#define INSERT(m_, v_) do {                                                  \
        unsigned g_i  = (unsigned)(m_);                                      \
        unsigned lb_i = g_i >> BIN_SHIFT;                                    \
        unsigned cv_i = atomicAdd(&cd[lb_i], 1u);                            \
        unsigned pos_i = cv_i & 0xFFFFu;                                     \
        unsigned drn_i = cv_i >> 16;                                         \
        if (pos_i - drn_i < DEPTH)                                           \
            bkt[lb_i * BSTRIDE + (pos_i % DEPTH)] =                          \
                ((g_i & ((1u << BIN_SHIFT) - 1u)) << 16) |                   \
                (unsigned)__half_as_ushort(__float2half_rn(v_));             \
    } while (0)

    // Flush one full 16-record (64-B) group at cursor d_: 4x ds_read_b128
    // (d_%48 in {0,16,32} -> contiguous, 16-B aligned) + 4x dwordx4 store.
#define FLUSH16(d_) do {                                                     \
        if ((d_) + 16u <= CAP) {                                             \
            unsigned s0_f = (d_) % DEPTH;                                    \
            const unsigned* bs_f = &bkt[(unsigned)t * BSTRIDE + s0_f];       \
            uintx4 r0_f = *(const uintx4*)(bs_f + 0);                        \
            uintx4 r1_f = *(const uintx4*)(bs_f + 4);                        \
            uintx4 r2_f = *(const uintx4*)(bs_f + 8);                        \
            uintx4 r3_f = *(const uintx4*)(bs_f + 12);                       \
            uintx4* dst_f = (uintx4*)(segp + (d_));                          \
            dst_f[0] = r0_f; dst_f[1] = r1_f;                                \
            dst_f[2] = r2_f; dst_f[3] = r3_f;                                \
        }                                                                    \
    } while (0)

    // Barriers on BOTH sides: inserts never overlap the owner's gather.
#define DRAIN() do {                                                         \
        __syncthreads();                                                     \
        if (t < LBINS) {                                                     \
            unsigned v_d = cd[t];                                            \
            unsigned c_d = v_d & 0xFFFFu, d_d = v_d >> 16;                   \
            if (c_d - d_d >= 16u) {                                          \
                FLUSH16(d_d);                                                \
                cd[t] = v_d + (16u << 16);                                   \
            }                                                                \
        }                                                                    \
        __syncthreads();                                                     \
    } while (0)

    // Software-pipelined input; 2 inserts per phase, 32 phases.
    int4   m = m4[t];
    float4 u = u4[t];
    for (int k = 0; k < BP_ITERS; ++k) {
        int4 mn = m; float4 un = u;
        if (k + 1 < BP_ITERS) {
            mn = m4[(k + 1) * BPT + t];
            un = u4[(k + 1) * BPT + t];
        }
        INSERT(m.x, u.x); INSERT(m.y, u.y); DRAIN();
        INSERT(m.z, u.z); INSERT(m.w, u.w); DRAIN();
        m = mn; u = un;
    }

    // Tail: pending <= 47 (up to 2 full groups + < 16 singles).
    if (t < LBINS) {
        unsigned v = cd[t];
        unsigned c = v & 0xFFFFu, d = v >> 16;
        unsigned pending = c - d;
        if (pending > DEPTH) pending = DEPTH;    // only if drops occurred
        while (pending >= 16u) {
            FLUSH16(d);
            d += 16u; pending -= 16u;
        }
        for (unsigned i = 0u; i < pending; ++i)   // d%48 + i <= 47: no wrap
            if (d + i < CAP)
                segp[d + i] = bkt[(unsigned)t * BSTRIDE + ((d + i) % DEPTH)];
        unsigned total = d + pending;
        if (total > CAP) total = CAP;
        cnt[(batch << 13) | (cc << CAP_SHIFT) | (unsigned)t] = total;
    }
#undef INSERT
#undef FLUSH16
#undef DRAIN
}

// One bin (64 KiB out-region) per block; its 32 segments are one contiguous
// 32-KiB region. Loads exec-masked past each segment's live prefix (dead
// 64-B lines never fetched). 1024 threads + 64 KiB LDS -> 2 blocks/CU,
// 32 waves (full occupancy). Segment counts read direct from L2-cached cnt.
__global__ __launch_bounds__(ACC_T) void accum_kernel(
    const unsigned* __restrict__ records, const unsigned* __restrict__ cnt,
    float* __restrict__ out)
{
    __shared__ float acc[1 << BIN_SHIFT];     // 64 KiB (exactly at cap)
    const int t = threadIdx.x;
    const unsigned bin   = blockIdx.x;        // [0, 4096)
    const unsigned batch = bin >> LBIN_SH;
    const unsigned lb    = bin & (LBINS - 1u);

    floatx4* accv = (floatx4*)acc;
    #pragma unroll
    for (int i = 0; i < (1 << BIN_SHIFT) / 4 / ACC_T; ++i)   // 4
        accv[i * ACC_T + t] = (floatx4)(0.f);
    __syncthreads();

    const uintx4* rec = (const uintx4*)(records + ((size_t)bin << 13));
    #pragma unroll
    for (int i = 0; i < (SEGS << CAP_SHIFT) / 4 / ACC_T; ++i) {   // 2
        unsigned q  = (unsigned)(i * ACC_T + t);    // uintx4 index in [0,2048)
        unsigned s  = q >> (CAP_SHIFT - 2);         // segment 0..31
        unsigned j0 = (q & ((1u << (CAP_SHIFT - 2)) - 1u)) << 2;
        unsigned n  = cnt[(batch << 13) | (s << CAP_SHIFT) | lb];
        if (j0 < n) {                               // skip dead lines entirely
            uintx4 v = __builtin_nontemporal_load(&rec[q]);
            atomicAdd(&acc[v.x >> 16],              // j0 < n guaranteed
                __half2float(__ushort_as_half((unsigned short)(v.x & 0xFFFFu))));
            if (j0 + 1u < n) atomicAdd(&acc[v.y >> 16],
                __half2float(__ushort_as_half((unsigned short)(v.y & 0xFFFFu))));
            if (j0 + 2u < n) atomicAdd(&acc[v.z >> 16],
                __half2float(__ushort_as_half((unsigned short)(v.z & 0xFFFFu))));
            if (j0 + 3u < n) atomicAdd(&acc[v.w >> 16],
                __half2float(__ushort_as_half((unsigned short)(v.w & 0xFFFFu))));
        }
    }
    __syncthreads();

    floatx4* dst = (floatx4*)(out + ((size_t)bin << BIN_SHIFT));
    #pragma unroll
    for (int i = 0; i < (1 << BIN_SHIFT) / 4 / ACC_T; ++i)   // 4
        __builtin_nontemporal_store(accv[i * ACC_T + t], &dst[i * ACC_T + t]);
}

// ---------------- launcher ----------------

extern "C" void kernel_launch(void* const* d_in, const int* in_sizes, int n_in,
                              void* d_out, int out_size, void* d_ws, size_t ws_size,
                              hipStream_t stream) {
    const float* upd  = (const float*)d_in[0];
    const int*   mask = (const int*)d_in[1];
    float*       out  = (float*)d_out;

    int n = in_sizes[0];

    // ws layout: cnt (2^17 u32 = 512 KiB, region 1 MiB) | records (128 MiB)
    size_t off_records = (size_t)1 << 20;
    size_t needed      = off_records + ((size_t)1 << 25) * 4;

    if ((unsigned)n == N_ELEMS && ws_size >= needed) {
        unsigned* cnt     = (unsigned*)d_ws;
        unsigned* records = (unsigned*)((char*)d_ws + off_records);

        binplace_kernel<<<NB,    BPT,   0, stream>>>((const float4*)upd, (const int4*)mask,
                                                     cnt, records);
        accum_kernel   <<<NBINS, ACC_T, 0, stream>>>(records, cnt, out);
    } else {
        // Fallback: zero + direct global atomics (round-2 design).
        int n4   = n / 4;
        int out4 = out_size / 4;
        zero_out_kernel<<<(out4 + 255) / 256, 256, 0, stream>>>((float4*)out, out4);
        maxunpool_scatter_kernel<<<(n4 + 255) / 256, 256, 0, stream>>>(
            (const float4*)upd, (const int4*)mask, out, n4);
    }
}

// Round 8
// 443.818 us; speedup vs baseline: 1.0152x; 1.0008x over previous
//
#include <hip/hip_runtime.h>
#include <hip/hip_fp16.h>

// MaxUnpooling2D scatter-add, LDS-bucketed binning with full-line flushes.
//
// updates: [16,128,128,64] fp32 = 2^24 elements (64 MiB)
// mask:    int32-staged, values in [0, 2^22) per batch
// out:     [16,256,256,64] fp32 = 2^26 elements (256 MiB)
//
// Round-13. Rounds 4/5/7 (443/450/444 us) -- three structurally different
// binplace versions, identical totals. The invariant: __syncthreads() at
// every phase drains vmcnt(0), killing the software-pipelined input
// prefetch 64x per block (HBM stream serialized against LDS phases).
// THIS round's single change: DRAIN barriers use raw s_barrier with
// explicit lgkmcnt(0)-only wait (m201-verified pattern):
//     asm volatile("s_waitcnt lgkmcnt(0)" ::: "memory");
//     __builtin_amdgcn_s_barrier();
// LDS cross-wave visibility needs only lgkmcnt; input prefetch loads and
// record flush stores stay in flight across barriers (vmcnt never drained
// in-loop). Everything else identical to round-12:
//  - circular 48-slot buckets, [bin][slot] stride 52, 53 KiB LDS.
//  - packed counter cd[bin] = count | drained<<16 (ds_add_rtn gives
//    position AND overflow bound).
//  - 2 inserts/phase, 32 phases; drain by threads<256 only.
//    lambda=4/bin/phase, headroom 32 -> overflow p ~ 1e-19. Safe.
//  - accum: 64 KiB acc + 1024 threads, 2 blocks/CU, counts from L2.
// Records [batch][lb][chunk][slot]; accum reads one contiguous 32-KiB
// region per bin, exec-masked past each segment's live prefix.
//  - 4-byte records: (14-bit bin-local offset << 16) | fp16 value.

#define N_ELEMS   (1u << 24)

// binplace geometry
#define NB        512                    // chunks (32 per batch)
#define BPT       512                    // binplace block size
#define G4_PER_B  ((N_ELEMS / NB) / 4)   // 8192 int4 groups per chunk
#define BP_ITERS  (G4_PER_B / BPT)       // 16

// binning geometry
#define BIN_SHIFT 14                     // 16384 floats (64 KiB) out-region per bin
#define LBINS     256                    // bins per batch
#define LBIN_SH   8
#define NBINS     4096                   // 16 batches * 256
#define CAP_SHIFT 8                      // 256 record slots per (bin,chunk) segment
#define CAP       (1u << CAP_SHIFT)
#define SEGS      32                     // chunks per batch
#define SEG_SH    5

#define DEPTH     48u                    // circular bucket slots per bin
#define BSTRIDE   52u                    // padded stride (words)

#define ACC_T     1024                   // accum block size

typedef float    floatx4 __attribute__((ext_vector_type(4)));
typedef unsigned uintx4  __attribute__((ext_vector_type(4)));

// lgkmcnt-only workgroup barrier: does NOT drain vmcnt, so in-flight
// global prefetch loads / record stores survive the phase boundary.
#define LDS_BARRIER() do {                                      \
        asm volatile("s_waitcnt lgkmcnt(0)" ::: "memory");      \
        __builtin_amdgcn_s_barrier();                           \
    } while (0)

// ---------------- fallback (round-2 design) ----------------

__global__ __launch_bounds__(256) void zero_out_kernel(float4* __restrict__ out, int n4)
{
    int i = blockIdx.x * blockDim.x + threadIdx.x;
    if (i < n4) out[i] = make_float4(0.f, 0.f, 0.f, 0.f);
}

__global__ __launch_bounds__(256) void maxunpool_scatter_kernel(
    const float4* __restrict__ upd, const int4* __restrict__ mask,
    float* __restrict__ out, int n4)
{
    int i = blockIdx.x * blockDim.x + threadIdx.x;
    if (i >= n4) return;
    float4 u = upd[i];
    int4   m = mask[i];
    long long base = (long long)(i >> 18) << 22;
    atomicAdd(out + base + m.x, u.x);
    atomicAdd(out + base + m.y, u.y);
    atomicAdd(out + base + m.z, u.z);
    atomicAdd(out + base + m.w, u.w);
}

// ---------------- binned pipeline ----------------

// records word offset: batch<<21 | lb<<13 | cc<<8 | slot  (2^25 words = 128 MiB)
// cnt     word offset: batch<<13 | cc<<8  | lb            (2^17 words = 512 KiB)

__global__ __launch_bounds__(BPT) void binplace_kernel(
    const float4* __restrict__ upd4, const int4* __restrict__ mask4,
    unsigned* __restrict__ cnt, unsigned* __restrict__ records)
{
    __shared__ __align__(16) unsigned bkt[LBINS * BSTRIDE];  // 52 KiB
    __shared__ unsigned cd[LBINS];    // 1 KiB: count | drained<<16
    const int t = threadIdx.x;
    if (t < LBINS) cd[t] = 0u;
    __syncthreads();

    const unsigned chunk = blockIdx.x;
    const unsigned batch = chunk >> SEG_SH;
    const unsigned cc    = chunk & (SEGS - 1u);
    const int4*   m4 = mask4 + (size_t)chunk * G4_PER_B;
    const float4* u4 = upd4  + (size_t)chunk * G4_PER_B;

    // owner thread t (< LBINS) drains bin t into segment (batch, lb=t, cc)
    unsigned* __restrict__ segp =
        records + (batch << 21) + ((unsigned)t << 13) + (cc << CAP_SHIFT);

#define INSERT(m_, v_) do {                                                  \
        unsigned g_i  = (unsigned)(m_);                                      \
        unsigned lb_i = g_i >> BIN_SHIFT;                                    \
        unsigned cv_i = atomicAdd(&cd[lb_i], 1u);                            \
        unsigned pos_i = cv_i & 0xFFFFu;                                     \
        unsigned drn_i = cv_i >> 16;                                         \
        if (pos_i - drn_i < DEPTH)                                           \
            bkt[lb_i * BSTRIDE + (pos_i % DEPTH)] =                          \
                ((g_i & ((1u << BIN_SHIFT) - 1u)) << 16) |                   \
                (unsigned)__half_as_ushort(__float2half_rn(v_));             \
    } while (0)

    // Flush one full 16-record (64-B) group at cursor d_: 4x ds_read_b128
    // (d_%48 in {0,16,32} -> contiguous, 16-B aligned) + 4x dwordx4 store.
#define FLUSH16(d_) do {                                                     \
        if ((d_) + 16u <= CAP) {                                             \
            unsigned s0_f = (d_) % DEPTH;                                    \
            const unsigned* bs_f = &bkt[(unsigned)t * BSTRIDE + s0_f];       \
            uintx4 r0_f = *(const uintx4*)(bs_f + 0);                        \
            uintx4 r1_f = *(const uintx4*)(bs_f + 4);                        \
            uintx4 r2_f = *(const uintx4*)(bs_f + 8);                        \
            uintx4 r3_f = *(const uintx4*)(bs_f + 12);                       \
            uintx4* dst_f = (uintx4*)(segp + (d_));                          \
            dst_f[0] = r0_f; dst_f[1] = r1_f;                                \
            dst_f[2] = r2_f; dst_f[3] = r3_f;                                \
        }                                                                    \
    } while (0)

    // lgkmcnt-only barriers on BOTH sides: inserts never overlap the
    // owner's gather, but global vmcnt traffic flows freely across.
#define DRAIN() do {                                                         \
        LDS_BARRIER();                                                       \
        if (t < LBINS) {                                                     \
            unsigned v_d = cd[t];                                            \
            unsigned c_d = v_d & 0xFFFFu, d_d = v_d >> 16;                   \
            if (c_d - d_d >= 16u) {                                          \
                FLUSH16(d_d);                                                \
                cd[t] = v_d + (16u << 16);                                   \
            }                                                                \
        }                                                                    \
        LDS_BARRIER();                                                       \
    } while (0)

    // Software-pipelined input; 2 inserts per phase, 32 phases.
    int4   m = m4[t];
    float4 u = u4[t];
    for (int k = 0; k < BP_ITERS; ++k) {
        int4 mn = m; float4 un = u;
        if (k + 1 < BP_ITERS) {
            mn = m4[(k + 1) * BPT + t];
            un = u4[(k + 1) * BPT + t];
        }
        INSERT(m.x, u.x); INSERT(m.y, u.y); DRAIN();
        INSERT(m.z, u.z); INSERT(m.w, u.w); DRAIN();
        m = mn; u = un;
    }

    // Tail: pending <= 47 (up to 2 full groups + < 16 singles).
    if (t < LBINS) {
        unsigned v = cd[t];
        unsigned c = v & 0xFFFFu, d = v >> 16;
        unsigned pending = c - d;
        if (pending > DEPTH) pending = DEPTH;    // only if drops occurred
        while (pending >= 16u) {
            FLUSH16(d);
            d += 16u; pending -= 16u;
        }
        for (unsigned i = 0u; i < pending; ++i)   // d%48 + i <= 47: no wrap
            if (d + i < CAP)
                segp[d + i] = bkt[(unsigned)t * BSTRIDE + ((d + i) % DEPTH)];
        unsigned total = d + pending;
        if (total > CAP) total = CAP;
        cnt[(batch << 13) | (cc << CAP_SHIFT) | (unsigned)t] = total;
    }
#undef INSERT
#undef FLUSH16
#undef DRAIN
}

// One bin (64 KiB out-region) per block; its 32 segments are one contiguous
// 32-KiB region. Loads exec-masked past each segment's live prefix (dead
// 64-B lines never fetched). 1024 threads + 64 KiB LDS -> 2 blocks/CU,
// 32 waves (full occupancy). Segment counts read direct from L2-cached cnt.
__global__ __launch_bounds__(ACC_T) void accum_kernel(
    const unsigned* __restrict__ records, const unsigned* __restrict__ cnt,
    float* __restrict__ out)
{
    __shared__ float acc[1 << BIN_SHIFT];     // 64 KiB (exactly at cap)
    const int t = threadIdx.x;
    const unsigned bin   = blockIdx.x;        // [0, 4096)
    const unsigned batch = bin >> LBIN_SH;
    const unsigned lb    = bin & (LBINS - 1u);

    floatx4* accv = (floatx4*)acc;
    #pragma unroll
    for (int i = 0; i < (1 << BIN_SHIFT) / 4 / ACC_T; ++i)   // 4
        accv[i * ACC_T + t] = (floatx4)(0.f);
    __syncthreads();

    const uintx4* rec = (const uintx4*)(records + ((size_t)bin << 13));
    #pragma unroll
    for (int i = 0; i < (SEGS << CAP_SHIFT) / 4 / ACC_T; ++i) {   // 2
        unsigned q  = (unsigned)(i * ACC_T + t);    // uintx4 index in [0,2048)
        unsigned s  = q >> (CAP_SHIFT - 2);         // segment 0..31
        unsigned j0 = (q & ((1u << (CAP_SHIFT - 2)) - 1u)) << 2;
        unsigned n  = cnt[(batch << 13) | (s << CAP_SHIFT) | lb];
        if (j0 < n) {                               // skip dead lines entirely
            uintx4 v = __builtin_nontemporal_load(&rec[q]);
            atomicAdd(&acc[v.x >> 16],              // j0 < n guaranteed
                __half2float(__ushort_as_half((unsigned short)(v.x & 0xFFFFu))));
            if (j0 + 1u < n) atomicAdd(&acc[v.y >> 16],
                __half2float(__ushort_as_half((unsigned short)(v.y & 0xFFFFu))));
            if (j0 + 2u < n) atomicAdd(&acc[v.z >> 16],
                __half2float(__ushort_as_half((unsigned short)(v.z & 0xFFFFu))));
            if (j0 + 3u < n) atomicAdd(&acc[v.w >> 16],
                __half2float(__ushort_as_half((unsigned short)(v.w & 0xFFFFu))));
        }
    }
    __syncthreads();

    floatx4* dst = (floatx4*)(out + ((size_t)bin << BIN_SHIFT));
    #pragma unroll
    for (int i = 0; i < (1 << BIN_SHIFT) / 4 / ACC_T; ++i)   // 4
        __builtin_nontemporal_store(accv[i * ACC_T + t], &dst[i * ACC_T + t]);
}

// ---------------- launcher ----------------

extern "C" void kernel_launch(void* const* d_in, const int* in_sizes, int n_in,
                              void* d_out, int out_size, void* d_ws, size_t ws_size,
                              hipStream_t stream) {
    const float* upd  = (const float*)d_in[0];
    const int*   mask = (const int*)d_in[1];
    float*       out  = (float*)d_out;

    int n = in_sizes[0];

    // ws layout: cnt (2^17 u32 = 512 KiB, region 1 MiB) | records (128 MiB)
    size_t off_records = (size_t)1 << 20;
    size_t needed      = off_records + ((size_t)1 << 25) * 4;

    if ((unsigned)n == N_ELEMS && ws_size >= needed) {
        unsigned* cnt     = (unsigned*)d_ws;
        unsigned* records = (unsigned*)((char*)d_ws + off_records);

        binplace_kernel<<<NB,    BPT,   0, stream>>>((const float4*)upd, (const int4*)mask,
                                                     cnt, records);
        accum_kernel   <<<NBINS, ACC_T, 0, stream>>>(records, cnt, out);
    } else {
        // Fallback: zero + direct global atomics (round-2 design).
        int n4   = n / 4;
        int out4 = out_size / 4;
        zero_out_kernel<<<(out4 + 255) / 256, 256, 0, stream>>>((float4*)out, out4);
        maxunpool_scatter_kernel<<<(n4 + 255) / 256, 256, 0, stream>>>(
            (const float4*)upd, (const int4*)mask, out, n4);
    }
}

// Round 9
// 440.810 us; speedup vs baseline: 1.0221x; 1.0068x over previous
//
#include <hip/hip_runtime.h>
#include <hip/hip_fp16.h>

// MaxUnpooling2D scatter-add, LDS-bucketed binning + persistent pipelined accum.
//
// updates: [16,128,128,64] fp32 = 2^24 elements (64 MiB)
// mask:    int32-staged, values in [0, 2^22) per batch
// out:     [16,256,256,64] fp32 = 2^26 elements (256 MiB)
//
// Round-14. Rounds 4-8: four structurally different binplace versions, four
// identical totals (443-450 us) -> binplace has been ~40-50 us (near its
// 31-us traffic floor) since round 4. The invisible big term is accum at
// ~155-162 us (just under the 162.6-us fillBuffer top-5 cutoff), ~2.5x its
// ~65-us BW floor, because its phases serialize per block: zero -> barrier
// (vmcnt drain) -> dependent cnt->rec loads (~700 cy exposed) -> atomics ->
// store 64 KiB -> retire.
// THIS round: binplace reverted to round-4's byte-identical 443-us version
// (BIN_SHIFT 13). Accum rebuilt as PERSISTENT + DOUBLE-BUFFERED:
//  - 512 blocks x 1024 thr (exactly 2/CU resident, no tail), 16 bins each.
//  - 2 x 32 KiB LDS halves; per bin: prefetch next bin's records to regs
//    (issued BEFORE this bin's out-stores -> compiler's auto waitcnt for the
//    prefetch consumption is vmcnt(2)-style, never drains stores), scatter
//    from regs, lgkm-only barrier, {ds_read half h -> nontemporal out-store
//    || zero half h'}, lgkm-only barrier. Out-stores stay in flight across
//    bins; LDS half reuse needs only lgkm (stores carry data in VGPRs).
//  - dead-line skip dropped (r5 measured it neutral): record loads are
//    unconditional -> independent of cnt -> clean software pipeline.
//  - 4-byte records: (13-bit bin-local offset << 16) | fp16 value.

#define N_ELEMS   (1u << 24)

// binplace geometry
#define NB        512                    // chunks (32 per batch)
#define BPT       512                    // binplace block size
#define G4_PER_B  ((N_ELEMS / NB) / 4)   // 8192 int4 groups per chunk
#define BP_ITERS  (G4_PER_B / BPT)       // 16

// binning geometry
#define BIN_SHIFT 13                     // 8192 floats (32 KiB) out-region per bin
#define LBINS     512                    // bins per batch
#define LBIN_SH   9
#define NBINS     8192                   // 16 batches * 512
#define CAP_SHIFT 7                      // 128 record slots per (bin,chunk) segment
#define CAP       (1u << CAP_SHIFT)
#define SEGS      32                     // chunks per batch
#define SEG_SH    5

#define BKT_DEPTH 30u                    // LDS bucket slots per bin (binplace)

#define ABLK      512                    // accum persistent blocks
#define ACC_T     1024                   // accum block size
#define BINS_PER_BLK (NBINS / ABLK)      // 16

typedef float    floatx4 __attribute__((ext_vector_type(4)));
typedef unsigned uintx4  __attribute__((ext_vector_type(4)));

// lgkmcnt-only workgroup barrier: does NOT drain vmcnt, so in-flight global
// prefetch loads / out-stores survive the phase boundary.
#define LDS_BARRIER() do {                                      \
        asm volatile("s_waitcnt lgkmcnt(0)" ::: "memory");      \
        __builtin_amdgcn_s_barrier();                           \
    } while (0)

// ---------------- fallback (round-2 design) ----------------

__global__ __launch_bounds__(256) void zero_out_kernel(float4* __restrict__ out, int n4)
{
    int i = blockIdx.x * blockDim.x + threadIdx.x;
    if (i < n4) out[i] = make_float4(0.f, 0.f, 0.f, 0.f);
}

__global__ __launch_bounds__(256) void maxunpool_scatter_kernel(
    const float4* __restrict__ upd, const int4* __restrict__ mask,
    float* __restrict__ out, int n4)
{
    int i = blockIdx.x * blockDim.x + threadIdx.x;
    if (i >= n4) return;
    float4 u = upd[i];
    int4   m = mask[i];
    long long base = (long long)(i >> 18) << 22;
    atomicAdd(out + base + m.x, u.x);
    atomicAdd(out + base + m.y, u.y);
    atomicAdd(out + base + m.z, u.z);
    atomicAdd(out + base + m.w, u.w);
}

// ---------------- binned pipeline ----------------

// records word offset: batch<<21 | lb<<12 | cc<<7 | slot  (2^25 words = 128 MiB)
// cnt     word offset: batch<<14 | cc<<9  | lb            (2^18 words = 1 MiB)

// Round-4 binplace, byte-identical (benched 443.19 us total).
__global__ __launch_bounds__(BPT) void binplace_kernel(
    const float4* __restrict__ upd4, const int4* __restrict__ mask4,
    unsigned* __restrict__ cnt, unsigned* __restrict__ records)
{
    __shared__ unsigned bkt[BKT_DEPTH * LBINS];   // 60 KiB, [slot][bin]
    __shared__ unsigned lcnt[LBINS];              // 2 KiB, records in bucket
    const int t = threadIdx.x;
    lcnt[t] = 0u;
    __syncthreads();

    const unsigned chunk = blockIdx.x;
    const unsigned batch = chunk >> SEG_SH;
    const unsigned cc    = chunk & (SEGS - 1u);
    const int4*   m4 = mask4 + (size_t)chunk * G4_PER_B;
    const float4* u4 = upd4  + (size_t)chunk * G4_PER_B;

    // this thread's drain target: segment (batch, lb=t, cc)
    unsigned* __restrict__ segp =
        records + (batch << 21) + ((unsigned)t << 12) + (cc << CAP_SHIFT);
    unsigned gout = 0u;                           // flushed records (global cursor)

#define INSERT(m_, v_) do {                                                  \
        unsigned g_i  = (unsigned)(m_);                                      \
        unsigned lb_i = g_i >> BIN_SHIFT;                                    \
        unsigned pos_i = atomicAdd(&lcnt[lb_i], 1u);                         \
        if (pos_i < BKT_DEPTH)                                               \
            bkt[pos_i * LBINS + lb_i] =                                      \
                ((g_i & ((1u << BIN_SHIFT) - 1u)) << 16) |                   \
                (unsigned)__half_as_ushort(__float2half_rn(v_));             \
    } while (0)

#define DRAIN() do {                                                         \
        __syncthreads();                                                     \
        unsigned c_d = lcnt[t];                                              \
        if (c_d > BKT_DEPTH) c_d = BKT_DEPTH;                                \
        if (c_d >= 16u) {                                                    \
            if (gout + 16u <= CAP) {                                         \
                uintx4 r0, r1, r2, r3;                                       \
                r0.x = bkt[ 0u*LBINS+t]; r0.y = bkt[ 1u*LBINS+t];            \
                r0.z = bkt[ 2u*LBINS+t]; r0.w = bkt[ 3u*LBINS+t];            \
                r1.x = bkt[ 4u*LBINS+t]; r1.y = bkt[ 5u*LBINS+t];            \
                r1.z = bkt[ 6u*LBINS+t]; r1.w = bkt[ 7u*LBINS+t];            \
                r2.x = bkt[ 8u*LBINS+t]; r2.y = bkt[ 9u*LBINS+t];            \
                r2.z = bkt[10u*LBINS+t]; r2.w = bkt[11u*LBINS+t];            \
                r3.x = bkt[12u*LBINS+t]; r3.y = bkt[13u*LBINS+t];            \
                r3.z = bkt[14u*LBINS+t]; r3.w = bkt[15u*LBINS+t];            \
                uintx4* dst_d = (uintx4*)(segp + gout);                      \
                dst_d[0] = r0; dst_d[1] = r1; dst_d[2] = r2; dst_d[3] = r3;  \
            }                                                                \
            gout += 16u;                                                     \
            unsigned rem_d = c_d - 16u;                                      \
            for (unsigned i_d = 0u; i_d < rem_d; ++i_d)                      \
                bkt[i_d * LBINS + t] = bkt[(16u + i_d) * LBINS + t];         \
            lcnt[t] = rem_d;                                                 \
        }                                                                    \
        __syncthreads();                                                     \
    } while (0)

    // Software-pipelined input; one insert per thread per phase (64 phases).
    int4   m = m4[t];
    float4 u = u4[t];
    for (int k = 0; k < BP_ITERS; ++k) {
        int4 mn = m; float4 un = u;
        if (k + 1 < BP_ITERS) {
            mn = m4[(k + 1) * BPT + t];
            un = u4[(k + 1) * BPT + t];
        }
        INSERT(m.x, u.x); DRAIN();
        INSERT(m.y, u.y); DRAIN();
        INSERT(m.z, u.z); DRAIN();
        INSERT(m.w, u.w); DRAIN();
        m = mn; u = un;
    }

    // Tail: last DRAIN left < 16 pending for bin t.
    {
        unsigned r = lcnt[t];
        if (r > 15u) r = 15u;
        for (unsigned i = 0u; i < r; ++i)
            if (gout + i < CAP) segp[gout + i] = bkt[i * LBINS + t];
        unsigned total = gout + r;
        if (total > CAP) total = CAP;
        cnt[(batch << (SEG_SH + LBIN_SH)) | (cc << LBIN_SH) | (unsigned)t] = total;
    }
#undef INSERT
#undef DRAIN
}

// Persistent double-buffered accum: 512 blocks x 1024 threads (2/CU, all
// co-resident), 16 consecutive bins per block. Records for bin j+1 are
// prefetched to registers BEFORE bin j's out-stores are issued, so the
// compiler's automatic waitcnt for their consumption leaves the stores in
// flight; lgkm-only barriers never drain vmcnt. The LDS half being stored
// is free for reuse as soon as its ds_reads complete (data travels in
// VGPRs), so zeroing the other half overlaps the store drain.
__global__ __launch_bounds__(ACC_T) void accum_kernel(
    const unsigned* __restrict__ records, const unsigned* __restrict__ cnt,
    float* __restrict__ out)
{
    __shared__ float acc[2][1 << BIN_SHIFT];     // 2 x 32 KiB
    const int t = threadIdx.x;
    const unsigned s  = (unsigned)t >> 5;        // segment 0..31 (uintx4 q = t)
    const unsigned j0 = ((unsigned)t & 31u) << 2;

    unsigned b = blockIdx.x * BINS_PER_BLK;      // first bin of this block

    // prologue: prefetch bin b's records + cnt, zero half 0
    uintx4   rc;
    unsigned nc;
    {
        unsigned batch = b >> LBIN_SH, lb = b & (LBINS - 1u);
        const uintx4* rp = (const uintx4*)(records + ((size_t)b << 12));
        rc = __builtin_nontemporal_load(&rp[t]);
        nc = cnt[(batch << (SEG_SH + LBIN_SH)) | (s << LBIN_SH) | lb];
    }
    {
        floatx4* a0 = (floatx4*)acc[0];
        a0[t] = (floatx4)(0.f);
        a0[t + ACC_T] = (floatx4)(0.f);
    }
    LDS_BARRIER();

    for (int j = 0; j < BINS_PER_BLK; ++j) {
        const unsigned h = (unsigned)j & 1u;

        // prefetch next bin (clamped; issued before this bin's stores)
        unsigned bn = b + 1u; if (bn >= NBINS) bn = NBINS - 1u;
        uintx4   rn;
        unsigned nn;
        {
            unsigned batchn = bn >> LBIN_SH, lbn = bn & (LBINS - 1u);
            const uintx4* rpn = (const uintx4*)(records + ((size_t)bn << 12));
            rn = __builtin_nontemporal_load(&rpn[t]);
            nn = cnt[(batchn << (SEG_SH + LBIN_SH)) | (s << LBIN_SH) | lbn];
        }

        // scatter current bin from registers into half h
        {
            float* ah = acc[h];
            if (j0 + 0u < nc) atomicAdd(&ah[rc.x >> 16],
                __half2float(__ushort_as_half((unsigned short)(rc.x & 0xFFFFu))));
            if (j0 + 1u < nc) atomicAdd(&ah[rc.y >> 16],
                __half2float(__ushort_as_half((unsigned short)(rc.y & 0xFFFFu))));
            if (j0 + 2u < nc) atomicAdd(&ah[rc.z >> 16],
                __half2float(__ushort_as_half((unsigned short)(rc.z & 0xFFFFu))));
            if (j0 + 3u < nc) atomicAdd(&ah[rc.w >> 16],
                __half2float(__ushort_as_half((unsigned short)(rc.w & 0xFFFFu))));
        }
        LDS_BARRIER();

        // store half h to out(bin b) (stays in flight); zero half h^1
        {
            floatx4* av = (floatx4*)acc[h];
            floatx4 v0 = av[t];
            floatx4 v1 = av[t + ACC_T];
            floatx4* aq = (floatx4*)acc[h ^ 1u];
            aq[t] = (floatx4)(0.f);
            aq[t + ACC_T] = (floatx4)(0.f);
            floatx4* dst = (floatx4*)(out + ((size_t)b << BIN_SHIFT));
            __builtin_nontemporal_store(v0, &dst[t]);
            __builtin_nontemporal_store(v1, &dst[t + ACC_T]);
        }
        LDS_BARRIER();

        // rotate software pipeline
        rc = rn; nc = nn; b = bn;
    }
}

// ---------------- launcher ----------------

extern "C" void kernel_launch(void* const* d_in, const int* in_sizes, int n_in,
                              void* d_out, int out_size, void* d_ws, size_t ws_size,
                              hipStream_t stream) {
    const float* upd  = (const float*)d_in[0];
    const int*   mask = (const int*)d_in[1];
    float*       out  = (float*)d_out;

    int n = in_sizes[0];

    // ws layout: cnt (2^18 u32 = 1 MiB) | records (2^25 u32 = 128 MiB)
    size_t off_records = (size_t)1 << 20;
    size_t needed      = off_records + ((size_t)1 << 25) * 4;

    if ((unsigned)n == N_ELEMS && ws_size >= needed) {
        unsigned* cnt     = (unsigned*)d_ws;
        unsigned* records = (unsigned*)((char*)d_ws + off_records);

        binplace_kernel<<<NB,   BPT,   0, stream>>>((const float4*)upd, (const int4*)mask,
                                                    cnt, records);
        accum_kernel   <<<ABLK, ACC_T, 0, stream>>>(records, cnt, out);
    } else {
        // Fallback: zero + direct global atomics (round-2 design).
        int n4   = n / 4;
        int out4 = out_size / 4;
        zero_out_kernel<<<(out4 + 255) / 256, 256, 0, stream>>>((float4*)out, out4);
        maxunpool_scatter_kernel<<<(n4 + 255) / 256, 256, 0, stream>>>(
            (const float4*)upd, (const int4*)mask, out, n4);
    }
}